// Round 7
// baseline (308.188 us; speedup 1.0000x reference)
//
#include <hip/hip_runtime.h>
#include <hip/hip_bf16.h>

#define NN 40000
#define NE 640000
#define NB 157   // ceil(NN/256)

typedef __attribute__((ext_vector_type(8))) short bf16x8;
typedef __attribute__((ext_vector_type(4))) float f32x4;

static __device__ __forceinline__ unsigned short f2b(float f) {
    unsigned b = __float_as_uint(f);
    return (unsigned short)((b + 0x7FFFu + ((b >> 16) & 1u)) >> 16);
}
static __device__ __forceinline__ float blo(unsigned v) { return __uint_as_float(v << 16); }
static __device__ __forceinline__ float bhi(unsigned v) { return __uint_as_float(v & 0xffff0000u); }

static __device__ __forceinline__ void acc4(float* a, uint2 v) {
    a[0] += blo(v.x); a[1] += bhi(v.x);
    a[2] += blo(v.y); a[3] += bhi(v.y);
}

// ---------------- CSR build ----------------

__global__ void count_deg_kernel(const int* __restrict__ dst, int* __restrict__ deg, int n) {
    int i = blockIdx.x * blockDim.x + threadIdx.x;
    if (i < n) atomicAdd(&deg[dst[i]], 1);
}

__global__ __launch_bounds__(256) void scan1_kernel(const int* __restrict__ deg,
                                                    int* __restrict__ bsum) {
    int i = blockIdx.x * 256 + threadIdx.x;
    int v = (i < NN) ? deg[i] : 0;
#pragma unroll
    for (int off = 1; off < 64; off <<= 1) v += __shfl_xor(v, off);
    __shared__ int ws4[4];
    if ((threadIdx.x & 63) == 0) ws4[threadIdx.x >> 6] = v;
    __syncthreads();
    if (threadIdx.x == 0) bsum[blockIdx.x] = ws4[0] + ws4[1] + ws4[2] + ws4[3];
}

__global__ void scan_top_kernel(const int* __restrict__ bsum, int* __restrict__ btop) {
    int lane = threadIdx.x;
    int run = 0;
    for (int base = 0; base < NB; base += 64) {
        int idx = base + lane;
        int v = (idx < NB) ? bsum[idx] : 0;
        int s = v;
#pragma unroll
        for (int off = 1; off < 64; off <<= 1) { int t = __shfl_up(s, off); if (lane >= off) s += t; }
        if (idx < NB) btop[idx] = run + s - v;
        run += __shfl(s, 63);
    }
}

__global__ __launch_bounds__(256) void scan2_kernel(const int* __restrict__ deg,
                                                    const int* __restrict__ btop,
                                                    int* __restrict__ row_ptr) {
    int b = blockIdx.x;
    int i = b * 256 + threadIdx.x;
    int lane = threadIdx.x & 63, wv = threadIdx.x >> 6;
    int v = (i < NN) ? deg[i] : 0;
    int s = v;
#pragma unroll
    for (int off = 1; off < 64; off <<= 1) { int t = __shfl_up(s, off); if (lane >= off) s += t; }
    __shared__ int wsum[4];
    if (lane == 63) wsum[wv] = s;
    __syncthreads();
    int add = btop[b];
    for (int w = 0; w < wv; ++w) add += wsum[w];
    if (i < NN) row_ptr[i] = add + s - v;
    if (i == NN - 1) row_ptr[NN] = add + s;
}

__global__ void fill_csr_kernel(const int* __restrict__ src, const int* __restrict__ dst,
                                const int* __restrict__ row_ptr, int* __restrict__ cursor,
                                int* __restrict__ csr, int n) {
    int i = blockIdx.x * blockDim.x + threadIdx.x;
    if (i < n) {
        int d = dst[i];
        int pos = row_ptr[d] + atomicAdd(&cursor[d], 1);
        csr[pos] = src[i];
    }
}

// ---------------- fused prep: zero deg/cursor + cast x + build weights ----------------

__global__ __launch_bounds__(256) void prep_kernel(
    const float* __restrict__ x,
    const float* __restrict__ Ws0, const float* __restrict__ Wn0,
    const float* __restrict__ Ws1, const float* __restrict__ Wn1,
    const float* __restrict__ Ws2, const float* __restrict__ Wn2,
    int* __restrict__ zero_base, unsigned short* __restrict__ X,
    unsigned short* __restrict__ Wt0, unsigned short* __restrict__ Wt1,
    unsigned short* __restrict__ Wt2s, unsigned short* __restrict__ Wt2n) {
    int b = blockIdx.x, tid = threadIdx.x;
    if (b < 79) {
        int i = (b * 256 + tid) * 4;
        if (i < 80000) *(int4*)(zero_base + i) = (int4){0, 0, 0, 0};
    } else if (b < 5079) {
        int i = (b - 79) * 256 + tid;   // one per 4 elems of x
        int e = i << 2;
        float4 v = *(const float4*)(x + e);
        uint2 o;
        o.x = f2b(v.x) | ((unsigned)f2b(v.y) << 16);
        o.y = f2b(v.z) | ((unsigned)f2b(v.w) << 16);
        *(uint2*)(X + e) = o;   // X is [NN][128], same flat layout as x
    } else {
        int i = (b - 5079) * 256 + tid;
        if (i < 65536) {
            // Wt0/Wt1: [128 n][256 k], k<128 = Ws rows, k>=128 = Wn rows
            int l = i >> 15, j = i & 32767;
            int n = j >> 8, k = j & 255;
            const float* Ws = l ? Ws1 : Ws0;
            const float* Wn = l ? Wn1 : Wn0;
            float v = (k < 128) ? Ws[k * 128 + n] : Wn[(k - 128) * 128 + n];
            (l ? Wt1 : Wt0)[n * 256 + k] = f2b(v);
        } else if (i < 65536 + 6144) {
            int j = i - 65536;                  // Wt2s: [48 n][128 k]
            int n = j >> 7, k = j & 127;
            float v = (n < 47) ? Ws2[k * 47 + n] : 0.f;
            Wt2s[n * 128 + k] = f2b(v);
        } else if (i < 65536 + 12288) {
            int j = i - 65536 - 6144;           // Wt2n: [48 n][128 k]
            int n = j >> 7, k = j & 127;
            float v = (n < 47) ? Wn2[k * 47 + n] : 0.f;
            Wt2n[n * 128 + k] = f2b(v);
        }
    }
}

// ---------------- fused SAGE layer: 16 nodes/block, col-split gather->LDS, MFMA ----------------
// Hin/Hout: [NN][128] bf16. Wt: [128 n][256 k] (k<128 self, k>=128 neigh).
// 256 threads / 4 waves. Gather is done in 4 COLUMN PASSES of 64B/edge so the
// touched line set per pass (40000 x 64B = 2.56 MB) is L2-resident per XCD.

template <bool RELU>
__global__ __launch_bounds__(256) void sage_layer_kernel(
    const unsigned short* __restrict__ Hin,
    const int* __restrict__ csr, const int* __restrict__ row_ptr,
    const unsigned short* __restrict__ Wt, const float* __restrict__ bias,
    unsigned short* __restrict__ Hout) {
    // [16 rows][16 chunks of 16B], chunk XOR-swizzled by row to kill bank conflicts
    __shared__ unsigned short agg_lds[16 * 128];

    int tid = threadIdx.x;
    int wv = tid >> 6, lane = tid & 63;
    int lr = lane & 15, lg = lane >> 4;
    int m0 = blockIdx.x * 16;

    // phase 1: gather-mean, 4 nodes per wave; 4 column passes of 32 cols (64B/edge)
    int nb = m0 + wv * 4;
    int rp5 = (lane < 5) ? row_ptr[nb + lane] : 0;
#pragma unroll
    for (int c = 0; c < 4; ++c) {
        const unsigned short* Hc = Hin + c * 32;
        for (int t = 0; t < 4; ++t) {
            int beg = __shfl(rp5, t), end = __shfl(rp5, t + 1);
            float a0 = 0.f, a1 = 0.f;
            int j = beg + lg;
            for (; j + 12 < end; j += 16) {
                int s0 = csr[j], s1 = csr[j + 4], s2 = csr[j + 8], s3 = csr[j + 12];
                unsigned v0 = *(const unsigned*)(Hc + (size_t)s0 * 128 + lr * 2);
                unsigned v1 = *(const unsigned*)(Hc + (size_t)s1 * 128 + lr * 2);
                unsigned v2 = *(const unsigned*)(Hc + (size_t)s2 * 128 + lr * 2);
                unsigned v3 = *(const unsigned*)(Hc + (size_t)s3 * 128 + lr * 2);
                a0 += blo(v0); a1 += bhi(v0);
                a0 += blo(v1); a1 += bhi(v1);
                a0 += blo(v2); a1 += bhi(v2);
                a0 += blo(v3); a1 += bhi(v3);
            }
            for (; j < end; j += 4) {
                unsigned v = *(const unsigned*)(Hc + (size_t)csr[j] * 128 + lr * 2);
                a0 += blo(v); a1 += bhi(v);
            }
            a0 += __shfl_xor(a0, 16); a0 += __shfl_xor(a0, 32);
            a1 += __shfl_xor(a1, 16); a1 += __shfl_xor(a1, 32);
            if (lg == 0) {
                float inv = 1.0f / fmaxf((float)(end - beg), 1.0f);
                unsigned w = f2b(a0 * inv) | ((unsigned)f2b(a1 * inv) << 16);
                int row = wv * 4 + t;
                int col = c * 32 + lr * 2;
                int chunk = (col >> 3) ^ row;           // swizzle (matches reader)
                *(unsigned*)&agg_lds[row * 128 + chunk * 8 + (col & 7)] = w;
            }
        }
    }
    __syncthreads();

    // phase 2: one 16-row M-tile; A = self(global) + neigh(LDS); B streamed from L2
    bf16x8 afr[8];
#pragma unroll
    for (int kt = 0; kt < 4; ++kt)
        afr[kt] = *(const bf16x8*)(Hin + (size_t)(m0 + lr) * 128 + kt * 32 + lg * 8);
#pragma unroll
    for (int kt = 0; kt < 4; ++kt) {
        int chunk = (kt * 4 + lg) ^ lr;                 // matching swizzle (row = lr)
        afr[4 + kt] = *(const bf16x8*)&agg_lds[lr * 128 + chunk * 8];
    }

    int n0 = (wv * 2) * 16 + lr;
    int n1 = n0 + 16;
    f32x4 acc0 = (f32x4){0.f, 0.f, 0.f, 0.f};
    f32x4 acc1 = (f32x4){0.f, 0.f, 0.f, 0.f};
#pragma unroll
    for (int kt = 0; kt < 8; ++kt) {
        bf16x8 b0 = *(const bf16x8*)(Wt + (size_t)n0 * 256 + kt * 32 + lg * 8);
        bf16x8 b1 = *(const bf16x8*)(Wt + (size_t)n1 * 256 + kt * 32 + lg * 8);
        acc0 = __builtin_amdgcn_mfma_f32_16x16x32_bf16(afr[kt], b0, acc0, 0, 0, 0);
        acc1 = __builtin_amdgcn_mfma_f32_16x16x32_bf16(afr[kt], b1, acc1, 0, 0, 0);
    }

    float bs0 = bias[n0], bs1 = bias[n1];
#pragma unroll
    for (int r = 0; r < 4; ++r) {
        int m = m0 + lg * 4 + r;
        float v0 = acc0[r] + bs0;
        float v1 = acc1[r] + bs1;
        if (RELU) { v0 = fmaxf(v0, 0.f); v1 = fmaxf(v1, 0.f); }
        Hout[(size_t)m * 128 + n0] = f2b(v0);
        Hout[(size_t)m * 128 + n1] = f2b(v1);
    }
}

// ---------------- layer-2 dual GEMM: one read of h2 -> out(self+bias) and Hn = h2@Wn2 ----------------
// 192 threads / 3 waves; wave wv owns tiles {2wv, 2wv+1} of 6 (0-2: self->out fp32, 3-5: neigh->Hn bf16)

__global__ __launch_bounds__(192) void dual_gemm_kernel(
    const unsigned short* __restrict__ H2,
    const unsigned short* __restrict__ Wt2s, const unsigned short* __restrict__ Wt2n,
    const float* __restrict__ b2,
    float* __restrict__ out, unsigned short* __restrict__ Hn) {
    int wv = threadIdx.x >> 6, lane = threadIdx.x & 63;
    int lr = lane & 15, lg = lane >> 4;

    bf16x8 bfr[2][4];
    float bs[2];
#pragma unroll
    for (int c = 0; c < 2; ++c) {
        int t = wv * 2 + c;
        bool is_s = t < 3;
        int n = (is_s ? t : t - 3) * 16 + lr;
        const unsigned short* W = is_s ? Wt2s : Wt2n;
#pragma unroll
        for (int kt = 0; kt < 4; ++kt)
            bfr[c][kt] = *(const bf16x8*)(W + (size_t)n * 128 + kt * 32 + lg * 8);
        bs[c] = (is_s && n < 47) ? b2[n] : 0.f;
    }

    for (int tt = 0; tt < 2; ++tt) {
        int m0 = blockIdx.x * 32 + tt * 16;
        bf16x8 afr[4];
#pragma unroll
        for (int kt = 0; kt < 4; ++kt)
            afr[kt] = *(const bf16x8*)(H2 + (size_t)(m0 + lr) * 128 + kt * 32 + lg * 8);
        f32x4 acc[2];
#pragma unroll
        for (int c = 0; c < 2; ++c) acc[c] = (f32x4){0.f, 0.f, 0.f, 0.f};
#pragma unroll
        for (int kt = 0; kt < 4; ++kt)
#pragma unroll
            for (int c = 0; c < 2; ++c)
                acc[c] = __builtin_amdgcn_mfma_f32_16x16x32_bf16(afr[kt], bfr[c][kt], acc[c], 0, 0, 0);
#pragma unroll
        for (int c = 0; c < 2; ++c) {
            int t = wv * 2 + c;
            bool is_s = t < 3;
            int n = (is_s ? t : t - 3) * 16 + lr;
#pragma unroll
            for (int r = 0; r < 4; ++r) {
                int m = m0 + lg * 4 + r;
                float v = acc[c][r] + bs[c];
                if (is_s) {
                    if (n < 47) out[(size_t)m * 47 + n] = v;
                } else {
                    Hn[(size_t)m * 48 + n] = f2b(v);   // cols>=47 are 0 (zeroed weights)
                }
            }
        }
    }
}

// ---------------- layer-2 neighbor mean in 47-col space, += into out ----------------
// Hn stride 48 (3.84 MB working set, ~L2-resident); 12 of 16 lanes carry cols.

__global__ void aggregate_out_kernel(const unsigned short* __restrict__ Hn,
                                     const int* __restrict__ csr,
                                     const int* __restrict__ row_ptr,
                                     float* __restrict__ out) {
    int node = (blockIdx.x * blockDim.x + threadIdx.x) >> 6;
    int lane = threadIdx.x & 63;
    if (node >= NN) return;
    int eg = lane >> 4, lc = lane & 15;
    int beg = row_ptr[node], end = row_ptr[node + 1];
    float a[4] = {};
    int j = beg + eg;
    for (; j + 12 < end; j += 16) {
        int s0 = csr[j], s1 = csr[j + 4], s2 = csr[j + 8], s3 = csr[j + 12];
        uint2 v0 = *(const uint2*)(Hn + (size_t)s0 * 48 + lc * 4);
        uint2 v1 = *(const uint2*)(Hn + (size_t)s1 * 48 + lc * 4);
        uint2 v2 = *(const uint2*)(Hn + (size_t)s2 * 48 + lc * 4);
        uint2 v3 = *(const uint2*)(Hn + (size_t)s3 * 48 + lc * 4);
        acc4(a, v0); acc4(a, v1); acc4(a, v2); acc4(a, v3);
    }
    for (; j < end; j += 4) {
        uint2 v = *(const uint2*)(Hn + (size_t)csr[j] * 48 + lc * 4);
        acc4(a, v);
    }
#pragma unroll
    for (int k = 0; k < 4; ++k) {
        a[k] += __shfl_xor(a[k], 16);
        a[k] += __shfl_xor(a[k], 32);
    }
    if (eg == 0 && lc < 12) {
        float inv = 1.0f / fmaxf((float)(end - beg), 1.0f);
        int c0 = lc * 4;
#pragma unroll
        for (int r = 0; r < 4; ++r)
            if (c0 + r < 47) out[(size_t)node * 47 + c0 + r] += a[r] * inv;
    }
}

// ---------------- launch ----------------

extern "C" void kernel_launch(void* const* d_in, const int* in_sizes, int n_in,
                              void* d_out, int out_size, void* d_ws, size_t ws_size,
                              hipStream_t stream) {
    const float* x   = (const float*)d_in[0];
    const int*   src = (const int*)d_in[1];
    const int*   dst = (const int*)d_in[2];
    const float* Ws0 = (const float*)d_in[3];
    const float* Wn0 = (const float*)d_in[4];
    const float* b0  = (const float*)d_in[5];
    const float* Ws1 = (const float*)d_in[6];
    const float* Wn1 = (const float*)d_in[7];
    const float* b1  = (const float*)d_in[8];
    const float* Ws2 = (const float*)d_in[9];
    const float* Wn2 = (const float*)d_in[10];
    const float* b2  = (const float*)d_in[11];
    float* out = (float*)d_out;

    int* wsI     = (int*)d_ws;
    int* deg     = wsI;                 // 40000
    int* cursor  = wsI + 40000;         // 40000
    int* row_ptr = wsI + 80000;         // 40001 (pad to 40004)
    int* csr     = wsI + 120004;        // 640000
    unsigned short* X   = (unsigned short*)(wsI + 760004);  // [40000][128]
    unsigned short* H1  = X + (size_t)NN * 128;             // [40000][128]
    unsigned short* H2  = X;                                // alias: X dead after layer 0
    unsigned short* Wt0 = H1 + (size_t)NN * 128;            // [128][256]
    unsigned short* Wt1 = Wt0 + 128 * 256;                  // [128][256]
    unsigned short* Wt2s = Wt1 + 128 * 256;                 // [48][128]
    unsigned short* Wt2n = Wt2s + 48 * 128;                 // [48][128]
    unsigned short* Hn  = Wt2n + 48 * 128;                  // [40000][48] + pad
    int* bsum = (int*)(Hn + (size_t)NN * 48 + 64);          // [NB]
    int* btop = bsum + NB;                                  // [NB]

    prep_kernel<<<5383, 256, 0, stream>>>(x, Ws0, Wn0, Ws1, Wn1, Ws2, Wn2,
                                          deg, X, Wt0, Wt1, Wt2s, Wt2n);
    count_deg_kernel<<<2500, 256, 0, stream>>>(dst, deg, NE);
    scan1_kernel<<<NB, 256, 0, stream>>>(deg, bsum);
    scan_top_kernel<<<1, 64, 0, stream>>>(bsum, btop);
    scan2_kernel<<<NB, 256, 0, stream>>>(deg, btop, row_ptr);
    fill_csr_kernel<<<2500, 256, 0, stream>>>(src, dst, row_ptr, cursor, csr, NE);

    sage_layer_kernel<true><<<2500, 256, 0, stream>>>(X, csr, row_ptr, Wt0, b0, H1);
    sage_layer_kernel<true><<<2500, 256, 0, stream>>>(H1, csr, row_ptr, Wt1, b1, H2);
    dual_gemm_kernel<<<1250, 192, 0, stream>>>(H2, Wt2s, Wt2n, b2, out, Hn);
    aggregate_out_kernel<<<10000, 256, 0, stream>>>(Hn, csr, row_ptr, out);
}

// Round 8
// 207.940 us; speedup vs baseline: 1.4821x; 1.4821x over previous
//
#include <hip/hip_runtime.h>
#include <hip/hip_bf16.h>

#define NN 40000
#define NE 640000
#define NB 157   // ceil(NN/256)

typedef __attribute__((ext_vector_type(8))) short bf16x8;
typedef __attribute__((ext_vector_type(4))) float f32x4;
typedef __attribute__((ext_vector_type(2))) float f32x2v;

static __device__ __forceinline__ unsigned short f2b(float f) {
    unsigned b = __float_as_uint(f);
    return (unsigned short)((b + 0x7FFFu + ((b >> 16) & 1u)) >> 16);
}
static __device__ __forceinline__ float blo(unsigned v) { return __uint_as_float(v << 16); }
static __device__ __forceinline__ float bhi(unsigned v) { return __uint_as_float(v & 0xffff0000u); }

static __device__ __forceinline__ void acc4(float* a, uint2 v) {
    a[0] += blo(v.x); a[1] += bhi(v.x);
    a[2] += blo(v.y); a[3] += bhi(v.y);
}

// ---------------- fp8 e4m3 encode/decode (HW cvt if available) ----------------

#if __has_builtin(__builtin_amdgcn_cvt_pk_fp8_f32) && __has_builtin(__builtin_amdgcn_cvt_pk_f32_fp8)
#define FP8_HW 1
#else
#define FP8_HW 0
#endif

static __device__ __forceinline__ unsigned char f2fp8_sw(float f) {
    f = fminf(fmaxf(f, -448.f), 448.f);
    unsigned b = __float_as_uint(f);
    unsigned s = (b >> 24) & 0x80u;
    unsigned ab = b & 0x7fffffffu;
    if (ab < 0x3c000000u) return (unsigned char)s;       // |f| < 2^-7 -> 0 (FTZ)
    unsigned r = ab + 0x7ffffu + ((ab >> 20) & 1u);      // RTN-even at 3-bit mantissa
    unsigned e = ((r >> 23) - 120u) & 0xfu;
    unsigned m = (r >> 20) & 7u;
    return (unsigned char)(s | (e << 3) | m);
}
static __device__ __forceinline__ float fp82f_sw(unsigned char u) {
    unsigned s = ((unsigned)u & 0x80u) << 24;
    unsigned e = (u >> 3) & 15u, m = u & 7u;
    float nrm = __uint_as_float(s | ((e + 120u) << 23) | (m << 20));
    float dnm = __uint_as_float(s | 0x3f800000u) * (float)m * 0.001953125f;
    return e ? nrm : dnm;
}

static __device__ __forceinline__ unsigned pack_fp8x4(float a, float b, float c, float d) {
#if FP8_HW
    int v = __builtin_amdgcn_cvt_pk_fp8_f32(a, b, 0, false);
    v = __builtin_amdgcn_cvt_pk_fp8_f32(c, d, v, true);
    return (unsigned)v;
#else
    return (unsigned)f2fp8_sw(a) | ((unsigned)f2fp8_sw(b) << 8) |
           ((unsigned)f2fp8_sw(c) << 16) | ((unsigned)f2fp8_sw(d) << 24);
#endif
}

// accumulate 8 fp8 cols (one uint2) into a[0..7]
static __device__ __forceinline__ void acc8f8(float* a, uint2 v) {
#if FP8_HW
    f32x2v p0 = __builtin_amdgcn_cvt_pk_f32_fp8((int)v.x, false);
    f32x2v p1 = __builtin_amdgcn_cvt_pk_f32_fp8((int)v.x, true);
    f32x2v p2 = __builtin_amdgcn_cvt_pk_f32_fp8((int)v.y, false);
    f32x2v p3 = __builtin_amdgcn_cvt_pk_f32_fp8((int)v.y, true);
    a[0] += p0.x; a[1] += p0.y; a[2] += p1.x; a[3] += p1.y;
    a[4] += p2.x; a[5] += p2.y; a[6] += p3.x; a[7] += p3.y;
#else
    a[0] += fp82f_sw(v.x & 0xff);         a[1] += fp82f_sw((v.x >> 8) & 0xff);
    a[2] += fp82f_sw((v.x >> 16) & 0xff); a[3] += fp82f_sw(v.x >> 24);
    a[4] += fp82f_sw(v.y & 0xff);         a[5] += fp82f_sw((v.y >> 8) & 0xff);
    a[6] += fp82f_sw((v.y >> 16) & 0xff); a[7] += fp82f_sw(v.y >> 24);
#endif
}

// ---------------- CSR build ----------------

__global__ void count_deg_kernel(const int* __restrict__ dst, int* __restrict__ deg, int n) {
    int i = blockIdx.x * blockDim.x + threadIdx.x;
    if (i < n) atomicAdd(&deg[dst[i]], 1);
}

__global__ __launch_bounds__(256) void scan1_kernel(const int* __restrict__ deg,
                                                    int* __restrict__ bsum) {
    int i = blockIdx.x * 256 + threadIdx.x;
    int v = (i < NN) ? deg[i] : 0;
#pragma unroll
    for (int off = 1; off < 64; off <<= 1) v += __shfl_xor(v, off);
    __shared__ int ws4[4];
    if ((threadIdx.x & 63) == 0) ws4[threadIdx.x >> 6] = v;
    __syncthreads();
    if (threadIdx.x == 0) bsum[blockIdx.x] = ws4[0] + ws4[1] + ws4[2] + ws4[3];
}

__global__ void scan_top_kernel(const int* __restrict__ bsum, int* __restrict__ btop) {
    int lane = threadIdx.x;
    int run = 0;
    for (int base = 0; base < NB; base += 64) {
        int idx = base + lane;
        int v = (idx < NB) ? bsum[idx] : 0;
        int s = v;
#pragma unroll
        for (int off = 1; off < 64; off <<= 1) { int t = __shfl_up(s, off); if (lane >= off) s += t; }
        if (idx < NB) btop[idx] = run + s - v;
        run += __shfl(s, 63);
    }
}

__global__ __launch_bounds__(256) void scan2_kernel(const int* __restrict__ deg,
                                                    const int* __restrict__ btop,
                                                    int* __restrict__ row_ptr) {
    int b = blockIdx.x;
    int i = b * 256 + threadIdx.x;
    int lane = threadIdx.x & 63, wv = threadIdx.x >> 6;
    int v = (i < NN) ? deg[i] : 0;
    int s = v;
#pragma unroll
    for (int off = 1; off < 64; off <<= 1) { int t = __shfl_up(s, off); if (lane >= off) s += t; }
    __shared__ int wsum[4];
    if (lane == 63) wsum[wv] = s;
    __syncthreads();
    int add = btop[b];
    for (int w = 0; w < wv; ++w) add += wsum[w];
    if (i < NN) row_ptr[i] = add + s - v;
    if (i == NN - 1) row_ptr[NN] = add + s;
}

__global__ void fill_csr_kernel(const int* __restrict__ src, const int* __restrict__ dst,
                                const int* __restrict__ row_ptr, int* __restrict__ cursor,
                                int* __restrict__ csr, int n) {
    int i = blockIdx.x * blockDim.x + threadIdx.x;
    if (i < n) {
        int d = dst[i];
        int pos = row_ptr[d] + atomicAdd(&cursor[d], 1);
        csr[pos] = src[i];
    }
}

// ---------------- fused prep: zero deg/cursor + cast x (bf16 + fp8) + build weights ----------------

__global__ __launch_bounds__(256) void prep_kernel(
    const float* __restrict__ x,
    const float* __restrict__ Ws0, const float* __restrict__ Wn0,
    const float* __restrict__ Ws1, const float* __restrict__ Wn1,
    const float* __restrict__ Ws2, const float* __restrict__ Wn2,
    int* __restrict__ zero_base, unsigned short* __restrict__ X,
    unsigned char* __restrict__ X8,
    unsigned short* __restrict__ Wt0, unsigned short* __restrict__ Wt1,
    unsigned short* __restrict__ Wt2s, unsigned short* __restrict__ Wt2n) {
    int b = blockIdx.x, tid = threadIdx.x;
    if (b < 79) {
        int i = (b * 256 + tid) * 4;
        if (i < 80000) *(int4*)(zero_base + i) = (int4){0, 0, 0, 0};
    } else if (b < 5079) {
        int i = (b - 79) * 256 + tid;   // one per 4 elems of x
        int e = i << 2;
        float4 v = *(const float4*)(x + e);
        uint2 o;
        o.x = f2b(v.x) | ((unsigned)f2b(v.y) << 16);
        o.y = f2b(v.z) | ((unsigned)f2b(v.w) << 16);
        *(uint2*)(X + e) = o;
        *(unsigned*)(X8 + e) = pack_fp8x4(v.x, v.y, v.z, v.w);
    } else {
        int i = (b - 5079) * 256 + tid;
        if (i < 65536) {
            // Wt0/Wt1: [128 n][256 k], k<128 = Ws rows, k>=128 = Wn rows
            int l = i >> 15, j = i & 32767;
            int n = j >> 8, k = j & 255;
            const float* Ws = l ? Ws1 : Ws0;
            const float* Wn = l ? Wn1 : Wn0;
            float v = (k < 128) ? Ws[k * 128 + n] : Wn[(k - 128) * 128 + n];
            (l ? Wt1 : Wt0)[n * 256 + k] = f2b(v);
        } else if (i < 65536 + 6144) {
            int j = i - 65536;                  // Wt2s: [48 n][128 k]
            int n = j >> 7, k = j & 127;
            float v = (n < 47) ? Ws2[k * 47 + n] : 0.f;
            Wt2s[n * 128 + k] = f2b(v);
        } else if (i < 65536 + 12288) {
            int j = i - 65536 - 6144;           // Wt2n: [48 n][128 k]
            int n = j >> 7, k = j & 127;
            float v = (n < 47) ? Wn2[k * 47 + n] : 0.f;
            Wt2n[n * 128 + k] = f2b(v);
        }
    }
}

// ---------------- fused SAGE layer: 16 nodes/block, fp8 gather->LDS, MFMA ----------------
// Hin: bf16 [NN][128] (self path, streaming). H8in: fp8 [NN][128] (gather path).
// Wt: [128 n][256 k] (k<128 self, k>=128 neigh). 256 threads / 4 waves.
// Each wave gathers 4 nodes (4 edge-groups x 16 lanes, 4 edges in flight),
// then owns 2 col-tiles of one 16-row M-tile. B streamed from L2.

template <bool RELU, bool WFP8>
__global__ __launch_bounds__(256) void sage_layer_kernel(
    const unsigned short* __restrict__ Hin, const unsigned char* __restrict__ H8in,
    const int* __restrict__ csr, const int* __restrict__ row_ptr,
    const unsigned short* __restrict__ Wt, const float* __restrict__ bias,
    unsigned short* __restrict__ Hout, unsigned char* __restrict__ H8out) {
    // [16 rows][16 chunks of 16B], chunk XOR-swizzled by row to kill bank conflicts
    __shared__ unsigned short agg_lds[16 * 128];

    int tid = threadIdx.x;
    int wv = tid >> 6, lane = tid & 63;
    int lr = lane & 15, lg = lane >> 4;
    int m0 = blockIdx.x * 16;

    // phase 1: gather-mean over fp8 rows (128 B/edge, 1 cache line)
    int nb = m0 + wv * 4;
    int rp5 = (lane < 5) ? row_ptr[nb + lane] : 0;
    for (int t = 0; t < 4; ++t) {
        int beg = __shfl(rp5, t), end = __shfl(rp5, t + 1);
        float a[8] = {};
        int j = beg + lg;
        for (; j + 12 < end; j += 16) {
            int s0 = csr[j], s1 = csr[j + 4], s2 = csr[j + 8], s3 = csr[j + 12];
            uint2 v0 = *(const uint2*)(H8in + (size_t)s0 * 128 + lr * 8);
            uint2 v1 = *(const uint2*)(H8in + (size_t)s1 * 128 + lr * 8);
            uint2 v2 = *(const uint2*)(H8in + (size_t)s2 * 128 + lr * 8);
            uint2 v3 = *(const uint2*)(H8in + (size_t)s3 * 128 + lr * 8);
            acc8f8(a, v0); acc8f8(a, v1); acc8f8(a, v2); acc8f8(a, v3);
        }
        for (; j < end; j += 4) {
            uint2 v = *(const uint2*)(H8in + (size_t)csr[j] * 128 + lr * 8);
            acc8f8(a, v);
        }
#pragma unroll
        for (int k = 0; k < 8; ++k) {
            a[k] += __shfl_xor(a[k], 16);
            a[k] += __shfl_xor(a[k], 32);
        }
        if (lg == 0) {
            float inv = 1.0f / fmaxf((float)(end - beg), 1.0f);
            uint4 o;
            o.x = f2b(a[0] * inv) | ((unsigned)f2b(a[1] * inv) << 16);
            o.y = f2b(a[2] * inv) | ((unsigned)f2b(a[3] * inv) << 16);
            o.z = f2b(a[4] * inv) | ((unsigned)f2b(a[5] * inv) << 16);
            o.w = f2b(a[6] * inv) | ((unsigned)f2b(a[7] * inv) << 16);
            int row = wv * 4 + t;
            int chunk = lr ^ row;                   // swizzle
            *(uint4*)&agg_lds[row * 128 + chunk * 8] = o;
        }
    }
    __syncthreads();

    // phase 2: one 16-row M-tile; A = self(global bf16) + neigh(LDS); B streamed from L2
    bf16x8 afr[8];
#pragma unroll
    for (int kt = 0; kt < 4; ++kt)
        afr[kt] = *(const bf16x8*)(Hin + (size_t)(m0 + lr) * 128 + kt * 32 + lg * 8);
#pragma unroll
    for (int kt = 0; kt < 4; ++kt) {
        int chunk = (kt * 4 + lg) ^ lr;             // matching swizzle (row = lr)
        afr[4 + kt] = *(const bf16x8*)&agg_lds[lr * 128 + chunk * 8];
    }

    int n0 = (wv * 2) * 16 + lr;
    int n1 = n0 + 16;
    f32x4 acc0 = (f32x4){0.f, 0.f, 0.f, 0.f};
    f32x4 acc1 = (f32x4){0.f, 0.f, 0.f, 0.f};
#pragma unroll
    for (int kt = 0; kt < 8; ++kt) {
        bf16x8 b0 = *(const bf16x8*)(Wt + (size_t)n0 * 256 + kt * 32 + lg * 8);
        bf16x8 b1 = *(const bf16x8*)(Wt + (size_t)n1 * 256 + kt * 32 + lg * 8);
        acc0 = __builtin_amdgcn_mfma_f32_16x16x32_bf16(afr[kt], b0, acc0, 0, 0, 0);
        acc1 = __builtin_amdgcn_mfma_f32_16x16x32_bf16(afr[kt], b1, acc1, 0, 0, 0);
    }

    float bs0 = bias[n0], bs1 = bias[n1];
#pragma unroll
    for (int r = 0; r < 4; ++r) {
        int m = m0 + lg * 4 + r;
        float v0 = acc0[r] + bs0;
        float v1 = acc1[r] + bs1;
        if (RELU) { v0 = fmaxf(v0, 0.f); v1 = fmaxf(v1, 0.f); }
        Hout[(size_t)m * 128 + n0] = f2b(v0);
        Hout[(size_t)m * 128 + n1] = f2b(v1);
        if (WFP8) {
#if FP8_HW
            H8out[(size_t)m * 128 + n0] =
                (unsigned char)(__builtin_amdgcn_cvt_pk_fp8_f32(v0, v0, 0, false) & 0xff);
            H8out[(size_t)m * 128 + n1] =
                (unsigned char)(__builtin_amdgcn_cvt_pk_fp8_f32(v1, v1, 0, false) & 0xff);
#else
            H8out[(size_t)m * 128 + n0] = f2fp8_sw(v0);
            H8out[(size_t)m * 128 + n1] = f2fp8_sw(v1);
#endif
        }
    }
}

// ---------------- layer-2 dual GEMM: one read of h2 -> out(self+bias) and Hn = h2@Wn2 ----------------

__global__ __launch_bounds__(192) void dual_gemm_kernel(
    const unsigned short* __restrict__ H2,
    const unsigned short* __restrict__ Wt2s, const unsigned short* __restrict__ Wt2n,
    const float* __restrict__ b2,
    float* __restrict__ out, unsigned short* __restrict__ Hn) {
    int wv = threadIdx.x >> 6, lane = threadIdx.x & 63;
    int lr = lane & 15, lg = lane >> 4;

    bf16x8 bfr[2][4];
    float bs[2];
#pragma unroll
    for (int c = 0; c < 2; ++c) {
        int t = wv * 2 + c;
        bool is_s = t < 3;
        int n = (is_s ? t : t - 3) * 16 + lr;
        const unsigned short* W = is_s ? Wt2s : Wt2n;
#pragma unroll
        for (int kt = 0; kt < 4; ++kt)
            bfr[c][kt] = *(const bf16x8*)(W + (size_t)n * 128 + kt * 32 + lg * 8);
        bs[c] = (is_s && n < 47) ? b2[n] : 0.f;
    }

    for (int tt = 0; tt < 2; ++tt) {
        int m0 = blockIdx.x * 32 + tt * 16;
        bf16x8 afr[4];
#pragma unroll
        for (int kt = 0; kt < 4; ++kt)
            afr[kt] = *(const bf16x8*)(H2 + (size_t)(m0 + lr) * 128 + kt * 32 + lg * 8);
        f32x4 acc[2];
#pragma unroll
        for (int c = 0; c < 2; ++c) acc[c] = (f32x4){0.f, 0.f, 0.f, 0.f};
#pragma unroll
        for (int kt = 0; kt < 4; ++kt)
#pragma unroll
            for (int c = 0; c < 2; ++c)
                acc[c] = __builtin_amdgcn_mfma_f32_16x16x32_bf16(afr[kt], bfr[c][kt], acc[c], 0, 0, 0);
#pragma unroll
        for (int c = 0; c < 2; ++c) {
            int t = wv * 2 + c;
            bool is_s = t < 3;
            int n = (is_s ? t : t - 3) * 16 + lr;
#pragma unroll
            for (int r = 0; r < 4; ++r) {
                int m = m0 + lg * 4 + r;
                float v = acc[c][r] + bs[c];
                if (is_s) {
                    if (n < 47) out[(size_t)m * 47 + n] = v;
                } else {
                    Hn[(size_t)m * 48 + n] = f2b(v);   // cols>=47 are 0 (zeroed weights)
                }
            }
        }
    }
}

// ---------------- layer-2 neighbor mean in 47-col space, += into out ----------------

__global__ void aggregate_out_kernel(const unsigned short* __restrict__ Hn,
                                     const int* __restrict__ csr,
                                     const int* __restrict__ row_ptr,
                                     float* __restrict__ out) {
    int node = (blockIdx.x * blockDim.x + threadIdx.x) >> 6;
    int lane = threadIdx.x & 63;
    if (node >= NN) return;
    int eg = lane >> 4, lc = lane & 15;
    int beg = row_ptr[node], end = row_ptr[node + 1];
    float a[4] = {};
    int j = beg + eg;
    for (; j + 12 < end; j += 16) {
        int s0 = csr[j], s1 = csr[j + 4], s2 = csr[j + 8], s3 = csr[j + 12];
        uint2 v0 = *(const uint2*)(Hn + (size_t)s0 * 48 + lc * 4);
        uint2 v1 = *(const uint2*)(Hn + (size_t)s1 * 48 + lc * 4);
        uint2 v2 = *(const uint2*)(Hn + (size_t)s2 * 48 + lc * 4);
        uint2 v3 = *(const uint2*)(Hn + (size_t)s3 * 48 + lc * 4);
        acc4(a, v0); acc4(a, v1); acc4(a, v2); acc4(a, v3);
    }
    for (; j < end; j += 4) {
        uint2 v = *(const uint2*)(Hn + (size_t)csr[j] * 48 + lc * 4);
        acc4(a, v);
    }
#pragma unroll
    for (int k = 0; k < 4; ++k) {
        a[k] += __shfl_xor(a[k], 16);
        a[k] += __shfl_xor(a[k], 32);
    }
    if (eg == 0 && lc < 12) {
        float inv = 1.0f / fmaxf((float)(end - beg), 1.0f);
        int c0 = lc * 4;
#pragma unroll
        for (int r = 0; r < 4; ++r)
            if (c0 + r < 47) out[(size_t)node * 47 + c0 + r] += a[r] * inv;
    }
}

// ---------------- launch ----------------

extern "C" void kernel_launch(void* const* d_in, const int* in_sizes, int n_in,
                              void* d_out, int out_size, void* d_ws, size_t ws_size,
                              hipStream_t stream) {
    const float* x   = (const float*)d_in[0];
    const int*   src = (const int*)d_in[1];
    const int*   dst = (const int*)d_in[2];
    const float* Ws0 = (const float*)d_in[3];
    const float* Wn0 = (const float*)d_in[4];
    const float* b0  = (const float*)d_in[5];
    const float* Ws1 = (const float*)d_in[6];
    const float* Wn1 = (const float*)d_in[7];
    const float* b1  = (const float*)d_in[8];
    const float* Ws2 = (const float*)d_in[9];
    const float* Wn2 = (const float*)d_in[10];
    const float* b2  = (const float*)d_in[11];
    float* out = (float*)d_out;

    int* wsI     = (int*)d_ws;
    int* deg     = wsI;                 // 40000
    int* cursor  = wsI + 40000;         // 40000
    int* row_ptr = wsI + 80000;         // 40001 (pad to 40004)
    int* csr     = wsI + 120004;        // 640000
    unsigned short* X   = (unsigned short*)(wsI + 760004);  // [40000][128] bf16
    unsigned short* H1  = X + (size_t)NN * 128;             // [40000][128] bf16
    unsigned short* H2  = X;                                // alias: X dead after layer 0
    unsigned short* Wt0 = H1 + (size_t)NN * 128;            // [128][256]
    unsigned short* Wt1 = Wt0 + 128 * 256;                  // [128][256]
    unsigned short* Wt2s = Wt1 + 128 * 256;                 // [48][128]
    unsigned short* Wt2n = Wt2s + 48 * 128;                 // [48][128]
    unsigned short* Hn  = Wt2n + 48 * 128;                  // [40000][48] bf16
    int* bsum = (int*)(Hn + (size_t)NN * 48 + 64);          // [NB]
    int* btop = bsum + NB;                                  // [NB]
    unsigned char* X8  = (unsigned char*)(btop + NB + 64);  // [40000][128] fp8
    unsigned char* H18 = X8 + (size_t)NN * 128;             // [40000][128] fp8

    prep_kernel<<<5383, 256, 0, stream>>>(x, Ws0, Wn0, Ws1, Wn1, Ws2, Wn2,
                                          deg, X, X8, Wt0, Wt1, Wt2s, Wt2n);
    count_deg_kernel<<<2500, 256, 0, stream>>>(dst, deg, NE);
    scan1_kernel<<<NB, 256, 0, stream>>>(deg, bsum);
    scan_top_kernel<<<1, 64, 0, stream>>>(bsum, btop);
    scan2_kernel<<<NB, 256, 0, stream>>>(deg, btop, row_ptr);
    fill_csr_kernel<<<2500, 256, 0, stream>>>(src, dst, row_ptr, cursor, csr, NE);

    sage_layer_kernel<true, true><<<2500, 256, 0, stream>>>(X, X8, csr, row_ptr, Wt0, b0, H1, H18);
    sage_layer_kernel<true, false><<<2500, 256, 0, stream>>>(H1, H18, csr, row_ptr, Wt1, b1, H2, nullptr);
    dual_gemm_kernel<<<1250, 192, 0, stream>>>(H2, Wt2s, Wt2n, b2, out, Hn);
    aggregate_out_kernel<<<10000, 256, 0, stream>>>(Hn, csr, row_ptr, out);
}